// Round 9
// baseline (510.111 us; speedup 1.0000x reference)
//
#include <hip/hip_runtime.h>

// VQGAN VectorQuantizer forward — block-owns-all-codes MFMA edition.
// z: (32,256,32,32) f32, emb: (1024,256) f32.
// d_out (float): [0..8388607] z_q | [8388608] loss | [8388609..] indices.
//
// Numerics: replicate np-f32 quantized score s = fl(fl(A+B) - 2*dot).
// dot via 3 bf16 MFMA GEMMs (z1e1+z1e2+z2e1; exact 2-term RNE splits), same
// fragment/accumulation order as rounds 6-8 (all passed). Rows with top-2
// margin < 1.5e-4 re-solved by k_refine (f32 dot, error ~1e-7 << 3e-5 grid)
// over all 1024 codes. Loss = 1.25 * mean best score.
//
// z_q region of d_out (dead until k_gather) holds z1t,z2t bf16 tiles (32 MB).
// ws scratch (~1.3 MB):
#define WS_B 0            // [1024]   B_k = ||emb_k||^2
#define WS_A 1024         // [32768]  A_n = ||z_n||^2
#define WS_E1 33792       // 262144 ushorts (e1 tiles)
#define WS_E2 164864      // 262144 ushorts (e2 tiles)
#define WS_LIST 295936    // [32768] int refine rows
#define WS_CNT 328704     // int refine count

#define DDIM 256
#define LOSS_OFF 8388608
#define IDX_OFF 8388609
#define Z2T_OFF 8388608   // ushort offset of z2t within out
#define REFINE_THR 1.5e-4f

typedef __attribute__((ext_vector_type(8))) short bf16x8;
typedef __attribute__((ext_vector_type(4))) float f32x4;
typedef __attribute__((ext_vector_type(8))) ushort u16x8;

__device__ __forceinline__ ushort bf16_rne(float x) {
  unsigned u = __float_as_uint(x);
  return (ushort)((u + 0x7FFFu + ((u >> 16) & 1u)) >> 16);
}
__device__ __forceinline__ float bf16f(ushort h) {
  return __uint_as_float(((unsigned)h) << 16);
}
__device__ __forceinline__ void gld16(void* l, const void* g) {
  __builtin_amdgcn_global_load_lds(
      (const __attribute__((address_space(1))) unsigned int*)g,
      (__attribute__((address_space(3))) unsigned int*)l, 16, 0, 0);
}

// ---------------- A: fused prep. blocks 0..255 = z, 256..259 = e ------------
__global__ __launch_bounds__(256) void k_prep(const float* __restrict__ z,
                                              const float* __restrict__ emb,
                                              float* __restrict__ out,
                                              float* __restrict__ ws) {
  __shared__ float lt[64][132];
  __shared__ float sq[128];
  const int tid = threadIdx.x;
  if (blockIdx.x >= 256) {
    // ---- eprep: one code per thread; tiles [ct4][s][kq][n 0..255][8] ----
    const int k = (blockIdx.x - 256) * 256 + tid;   // 0..1023
    if (k == 0) { out[LOSS_OFF] = 0.0f; ((int*)ws)[WS_CNT] = 0; }
    const int ct = k >> 8, n = k & 255;
    const float* er = emb + k * DDIM;
    ushort* e1t = (ushort*)(ws + WS_E1);
    ushort* e2t = (ushort*)(ws + WS_E2);
    float bsum = 0.f;
    for (int s = 0; s < 8; ++s) {
#pragma unroll
      for (int kq = 0; kq < 4; ++kq) {
        const float4 v0 = *(const float4*)(er + s * 32 + kq * 8);
        const float4 v1 = *(const float4*)(er + s * 32 + kq * 8 + 4);
        const float v[8] = {v0.x, v0.y, v0.z, v0.w, v1.x, v1.y, v1.z, v1.w};
        u16x8 h, l;
#pragma unroll
        for (int j = 0; j < 8; ++j) {
          bsum = fmaf(v[j], v[j], bsum);
          h[j] = bf16_rne(v[j]);
          l[j] = bf16_rne(v[j] - bf16f(h[j]));
        }
        const int off = ct * 65536 + s * 8192 + kq * 2048 + n * 8;
        *(u16x8*)(e1t + off) = h;
        *(u16x8*)(e2t + off) = l;
      }
    }
    ws[WS_B + k] = bsum;
    return;
  }
  // ---- zprep: tiles [rt128][s][kq][m 0..127][8] + A_n (identical to R8) ----
  const int rt = blockIdx.x;
  const int b = rt >> 3;
  const int hw0 = (rt & 7) << 7;
  ushort* z1t = (ushort*)out;
  ushort* z2t = (ushort*)out + Z2T_OFF;
  const int m = tid & 127, half = tid >> 7;
  const int lc = tid >> 2, lq = tid & 3;
  float as[4] = {0.f, 0.f, 0.f, 0.f};
  for (int p = 0; p < 4; ++p) {
    const float* src = z + b * 262144 + ((p << 6) + lc) * 1024 + hw0 + (lq << 5);
#pragma unroll
    for (int i = 0; i < 8; ++i)
      *(float4*)&lt[lc][(lq << 5) + (i << 2)] = *(const float4*)(src + (i << 2));
    __syncthreads();
    const int s = (p << 1) + half;
#pragma unroll
    for (int kq = 0; kq < 4; ++kq) {
      u16x8 h, l;
#pragma unroll
      for (int j = 0; j < 8; ++j) {
        const float v = lt[(half << 5) + (kq << 3) + j][m];
        as[j & 3] = fmaf(v, v, as[j & 3]);
        h[j] = bf16_rne(v);
        l[j] = bf16_rne(v - bf16f(h[j]));
      }
      const int off = rt * 32768 + ((s << 2) + kq) * 1024 + (m << 3);
      *(u16x8*)(z1t + off) = h;
      *(u16x8*)(z2t + off) = l;
    }
    __syncthreads();
  }
  const float asum = (as[0] + as[1]) + (as[2] + as[3]);
  if (half) sq[m] = asum;
  __syncthreads();
  if (!half) ws[WS_A + rt * 128 + m] = asum + sq[m];
}

// ---------------- B: MFMA score, one block = 128 rows x ALL 1024 codes ------
// 512 thr (8 waves 2x4; wave = 64 rows x 64 cols per ct-strip), 4 ct-strips of
// 256 cols, 8 K-steps each -> 32 steps. LDS 96 KB dbuf staged via
// global_load_lds; counted vmcnt(6); online top-2 fold at ct boundaries; one
// shuffle-reduce + cross-wave merge at the end; writes idx/gate/loss directly.
__global__ __launch_bounds__(512, 2) void k_score(float* out,
                                                  float* __restrict__ ws) {
  __shared__ __align__(16) ushort lds[2][24576];  // 2 x 48 KB
  __shared__ float Bs[1024];
  __shared__ float sm2[8];
  const int tid = threadIdx.x;
  const int rt = blockIdx.x;           // 0..255
  const int row0 = rt << 7;
  const ushort* z1t = (const ushort*)out;
  const ushort* z2t = (const ushort*)out + Z2T_OFF;
  const ushort* e1t = (const ushort*)(ws + WS_E1);
  const ushort* e2t = (const ushort*)(ws + WS_E2);
  const int w = tid >> 6, L = tid & 63;
  const int l15 = L & 15, kq = L >> 4;
  const int wr = w >> 2, wc = w & 3;

  // prologue loads: Bs (LDS), Av (regs)
  Bs[tid] = ws[WS_B + tid];
  Bs[tid + 512] = ws[WS_B + tid + 512];
  float Av[4][4];
#pragma unroll
  for (int mi = 0; mi < 4; ++mi)
#pragma unroll
    for (int r = 0; r < 4; ++r)
      Av[mi][r] = ws[WS_A + row0 + (wr << 6) + (mi << 4) + (kq << 2) + r];
  asm volatile("s_waitcnt vmcnt(0)" ::: "memory");
  __builtin_amdgcn_sched_barrier(0);
  __syncthreads();

  // staging bases: 48 x 1KB slabs per step; wave w owns flat slabs w*6..w*6+5
  const ushort* cbase[6];
  bool cisz[6];
#pragma unroll
  for (int c = 0; c < 6; ++c) {
    const int f = w * 6 + c;
    if (f < 8)       { cbase[c] = z1t + rt * 32768 + (f << 9) + (L << 3); cisz[c] = true; }
    else if (f < 16) { cbase[c] = z2t + rt * 32768 + ((f - 8) << 9) + (L << 3); cisz[c] = true; }
    else if (f < 32) { cbase[c] = e1t + ((f - 16) << 9) + (L << 3); cisz[c] = false; }
    else             { cbase[c] = e2t + ((f - 32) << 9) + (L << 3); cisz[c] = false; }
  }
  auto stage = [&](int q, int bf) {
    const int s = q & 7, ct = q >> 3;
    const int zoff = s << 12;                 // s*4096 ushorts
    const int eoff = (ct << 16) + (s << 13);  // ct*65536 + s*8192
#pragma unroll
    for (int c = 0; c < 6; ++c) {
      const ushort* src = cbase[c] + (cisz[c] ? zoff : eoff);
      gld16(&lds[bf][(w * 6 + c) << 9], src);
    }
  };

  f32x4 acc[4][4];
  float v1[4][4], v2[4][4];
  int i1[4][4];
#pragma unroll
  for (int mi = 0; mi < 4; ++mi)
#pragma unroll
    for (int r = 0; r < 4; ++r) {
      acc[mi][r] = (f32x4){0.f, 0.f, 0.f, 0.f};
      v1[mi][r] = 3.0e38f; v2[mi][r] = 3.0e38f; i1[mi][r] = 0;
    }

  stage(0, 0);
  stage(1, 1);

  auto body = [&](int q, int cur, bool last) {
    if (!last) asm volatile("s_waitcnt vmcnt(6)" ::: "memory");
    else       asm volatile("s_waitcnt vmcnt(0)" ::: "memory");
    __builtin_amdgcn_sched_barrier(0);
    __builtin_amdgcn_s_barrier();
    __builtin_amdgcn_sched_barrier(0);
    const ushort* lb = lds[cur];
    bf16x8 a1[4], a2[4], b1[4], b2[4];
#pragma unroll
    for (int mi = 0; mi < 4; ++mi) {
      const int off = (kq << 10) + (((wr << 6) + (mi << 4) + l15) << 3);
      a1[mi] = *(const bf16x8*)&lb[off];
      a2[mi] = *(const bf16x8*)&lb[4096 + off];
    }
#pragma unroll
    for (int nj = 0; nj < 4; ++nj) {
      const int off = (kq << 11) + (((wc << 6) + (nj << 4) + l15) << 3);
      b1[nj] = *(const bf16x8*)&lb[8192 + off];
      b2[nj] = *(const bf16x8*)&lb[16384 + off];
    }
    asm volatile("s_waitcnt lgkmcnt(0)" ::: "memory");
    __builtin_amdgcn_sched_barrier(0);
    __builtin_amdgcn_s_barrier();
    __builtin_amdgcn_sched_barrier(0);
    if (q < 30) stage(q + 2, cur);
    __builtin_amdgcn_s_setprio(1);
#pragma unroll
    for (int mi = 0; mi < 4; ++mi)
#pragma unroll
      for (int nj = 0; nj < 4; ++nj) {
        acc[mi][nj] = __builtin_amdgcn_mfma_f32_16x16x32_bf16(a2[mi], b1[nj], acc[mi][nj], 0, 0, 0);
        acc[mi][nj] = __builtin_amdgcn_mfma_f32_16x16x32_bf16(a1[mi], b2[nj], acc[mi][nj], 0, 0, 0);
        acc[mi][nj] = __builtin_amdgcn_mfma_f32_16x16x32_bf16(a1[mi], b1[nj], acc[mi][nj], 0, 0, 0);
      }
    __builtin_amdgcn_s_setprio(0);
    if ((q & 7) == 7) {   // ct-strip boundary: fold scores, reset acc
      const int ct = q >> 3;
      float bb[4];
#pragma unroll
      for (int nj = 0; nj < 4; ++nj)
        bb[nj] = Bs[(ct << 8) + (wc << 6) + (nj << 4) + l15];
#pragma unroll
      for (int mi = 0; mi < 4; ++mi)
#pragma unroll
        for (int nj = 0; nj < 4; ++nj) {
          const int kg = (ct << 8) + (wc << 6) + (nj << 4) + l15;
#pragma unroll
          for (int r = 0; r < 4; ++r) {
            const float sc = fmaf(-2.0f, acc[mi][nj][r], Av[mi][r] + bb[nj]);
            if (sc < v1[mi][r]) { v2[mi][r] = v1[mi][r]; v1[mi][r] = sc; i1[mi][r] = kg; }
            else if (sc < v2[mi][r]) v2[mi][r] = sc;
          }
          acc[mi][nj] = (f32x4){0.f, 0.f, 0.f, 0.f};
        }
    }
  };

  for (int q = 0; q < 31; ++q) body(q, q & 1, false);
  body(31, 1, true);

  // cross-l15 reduce (once per block)
#pragma unroll
  for (int mi = 0; mi < 4; ++mi)
#pragma unroll
    for (int r = 0; r < 4; ++r) {
      float a = v1[mi][r], bb = v2[mi][r];
      int ii = i1[mi][r];
#pragma unroll
      for (int o = 1; o < 16; o <<= 1) {
        const float oa = __shfl_xor(a, o);
        const float ob = __shfl_xor(bb, o);
        const int oi = __shfl_xor(ii, o);
        bb = fminf(fminf(bb, ob), fmaxf(a, oa));
        if (oa < a || (oa == a && oi < ii)) { a = oa; ii = oi; }
      }
      v1[mi][r] = a; v2[mi][r] = bb; i1[mi][r] = ii;
    }

  // cross-wave merge via LDS (staging done; reuse lds[0])
  __syncthreads();
  float* red = (float*)&lds[0][0];   // [4 wc][128 rows][3]
  if (l15 == 0) {
#pragma unroll
    for (int mi = 0; mi < 4; ++mi)
#pragma unroll
      for (int r = 0; r < 4; ++r) {
        const int rl = (wr << 6) + (mi << 4) + (kq << 2) + r;
        const int b3 = (wc * 128 + rl) * 3;
        red[b3] = v1[mi][r];
        red[b3 + 1] = v2[mi][r];
        red[b3 + 2] = (float)i1[mi][r];
      }
  }
  __syncthreads();
  float losss = 0.f;
  if (tid < 128) {
    float fv1 = 3.0e38f, fv2 = 3.0e38f;
    int fi = 0;
#pragma unroll
    for (int c = 0; c < 4; ++c) {
      const int b3 = (c * 128 + tid) * 3;
      const float a1 = red[b3], a2 = red[b3 + 1];
      const int ai = (int)red[b3 + 2];
      if (a1 < fv1 || (a1 == fv1 && ai < fi)) { fv2 = fminf(fv1, a2); fv1 = a1; fi = ai; }
      else fv2 = fminf(fv2, a1);
    }
    const int row = row0 + tid;
    out[IDX_OFF + row] = (float)fi;
    if (fv2 - fv1 < REFINE_THR) {
      const int slot = atomicAdd((int*)ws + WS_CNT, 1);
      ((int*)ws)[WS_LIST + slot] = row;
    }
    losss = fv1;
  }
#pragma unroll
  for (int o = 32; o; o >>= 1) losss += __shfl_down(losss, o);
  if ((tid & 63) == 0) sm2[tid >> 6] = losss;
  __syncthreads();
  if (tid == 0) {
    float t = 0.f;
#pragma unroll
    for (int i = 0; i < 8; ++i) t += sm2[i];
    atomicAdd(out + LOSS_OFF, t * (1.25f / 8388608.0f));
  }
}

// ---------------- B3: exact re-solve over all 1024 codes --------------------
__global__ __launch_bounds__(256) void k_refine(const float* __restrict__ z,
                                                const float* __restrict__ emb,
                                                const float* __restrict__ ws,
                                                float* __restrict__ out) {
  __shared__ float zs[4][256];
  const int tid = threadIdx.x;
  const int w = tid >> 6, L = tid & 63;
  const int wg = blockIdx.x * 4 + w;
  const int cnt = ((const int*)ws)[WS_CNT];
  for (int e = wg; e < cnt; e += 1024) {
    const int row = ((const int*)ws)[WS_LIST + e];
    const int b = row >> 10, hw = row & 1023;
#pragma unroll
    for (int q = 0; q < 4; ++q)
      zs[w][(q << 6) + L] = z[b * 262144 + (((q << 6) + L) << 10) + hw];
    asm volatile("s_waitcnt lgkmcnt(0)" ::: "memory");
    const float A = ws[WS_A + row];
    float bv = 3.0e38f;
    int bk = 0;
    for (int g = 0; g < 16; ++g) {
      const int k = (g << 6) + L;          // ascending per lane
      const float* er = emb + k * DDIM;
      float s0 = 0.f, s1 = 0.f, s2 = 0.f, s3 = 0.f;
      for (int d = 0; d < 64; ++d) {
        s0 = fmaf(zs[w][d], er[d], s0);
        s1 = fmaf(zs[w][d + 64], er[d + 64], s1);
        s2 = fmaf(zs[w][d + 128], er[d + 128], s2);
        s3 = fmaf(zs[w][d + 192], er[d + 192], s3);
      }
      const float dot = (s0 + s1) + (s2 + s3);
      const float sc = fmaf(-2.0f, dot, A + ws[WS_B + k]);
      if (sc < bv) { bv = sc; bk = k; }
    }
#pragma unroll
    for (int o = 1; o < 64; o <<= 1) {
      const float ov = __shfl_xor(bv, o);
      const int ok = __shfl_xor(bk, o);
      if (ov < bv || (ov == bv && ok < bk)) { bv = ov; bk = ok; }
    }
    if (L == 0) out[IDX_OFF + row] = (float)bk;
  }
}

// ---------------- C: z_q gather (pure) ----------------
__global__ __launch_bounds__(256) void k_gather(const float* __restrict__ emb,
                                                float* __restrict__ out) {
  const int tid = threadIdx.x;
  const int e0 = (blockIdx.x * 256 + tid) * 16;
  const int b = e0 >> 18;
  const int c = (e0 >> 10) & 255;
  const int n0 = (b << 10) + (e0 & 1023);
#pragma unroll
  for (int g = 0; g < 4; ++g) {
    float q[4];
#pragma unroll
    for (int j = 0; j < 4; ++j) {
      const int id = (int)(out[IDX_OFF + n0 + g * 4 + j] + 0.5f);
      q[j] = emb[id * DDIM + c];
    }
    const float4 qv = {q[0], q[1], q[2], q[3]};
    *(float4*)(out + e0 + g * 4) = qv;
  }
}

extern "C" void kernel_launch(void* const* d_in, const int* in_sizes, int n_in,
                              void* d_out, int out_size, void* d_ws, size_t ws_size,
                              hipStream_t stream) {
  const float* z = (const float*)d_in[0];
  const float* emb = (const float*)d_in[1];
  float* out = (float*)d_out;
  float* ws = (float*)d_ws;

  k_prep<<<260, 256, 0, stream>>>(z, emb, out, ws);
  k_score<<<256, 512, 0, stream>>>(out, ws);
  k_refine<<<256, 256, 0, stream>>>(z, emb, ws, out);
  k_gather<<<2048, 256, 0, stream>>>(emb, out);
}

// Round 10
// 162.321 us; speedup vs baseline: 3.1426x; 3.1426x over previous
//
#include <hip/hip_runtime.h>

// VQGAN VectorQuantizer forward — block-owns-all-codes MFMA + chunk-gated refine.
// z: (32,256,32,32) f32, emb: (1024,256) f32.
// d_out (float): [0..8388607] z_q | [8388608] loss | [8388609..] indices.
//
// Numerics: replicate np-f32 quantized score s = fl(fl(A+B) - 2*dot).
// dot via 3 bf16 MFMA GEMMs (z1e1+z1e2+z2e1; exact 2-term RNE splits), same
// fragment/accumulation order as rounds 6-9 (all passed). Rows with top-2
// margin < 1.5e-4 re-solved by k_refine (bit-exact round-3 serial-fmaf chain)
// over candidate 64-code chunks only (chunk_min <= v1 + THR: provable superset
// of np-preferable codes since per-code |s_np - s_mine| <= ~6.9e-5 < THR/2).
// Loss = 1.25 * mean best score.
//
// z_q region of d_out (dead until k_gather) holds z1t,z2t bf16 tiles (32 MB).
// ws scratch (~3.3 MB):
#define WS_B 0            // [1024]   B_k = ||emb_k||^2
#define WS_A 1024         // [32768]  A_n = ||z_n||^2
#define WS_PV 33792       // [16][32768] per-chunk best score (chunk c = codes 64c..64c+63)
#define WS_E1 558080      // 262144 ushorts (e1 tiles)
#define WS_E2 689152      // 262144 ushorts (e2 tiles)
#define WS_LIST 820224    // [32768] int refine rows
#define WS_CNT 852992     // int refine count

#define DDIM 256
#define LOSS_OFF 8388608
#define IDX_OFF 8388609
#define Z2T_OFF 8388608   // ushort offset of z2t within out
#define REFINE_THR 1.5e-4f

typedef __attribute__((ext_vector_type(8))) short bf16x8;
typedef __attribute__((ext_vector_type(4))) float f32x4;
typedef __attribute__((ext_vector_type(8))) ushort u16x8;

__device__ __forceinline__ ushort bf16_rne(float x) {
  unsigned u = __float_as_uint(x);
  return (ushort)((u + 0x7FFFu + ((u >> 16) & 1u)) >> 16);
}
__device__ __forceinline__ float bf16f(ushort h) {
  return __uint_as_float(((unsigned)h) << 16);
}
__device__ __forceinline__ void gld16(void* l, const void* g) {
  __builtin_amdgcn_global_load_lds(
      (const __attribute__((address_space(1))) unsigned int*)g,
      (__attribute__((address_space(3))) unsigned int*)l, 16, 0, 0);
}

// ---------------- A: fused prep. blocks 0..255 = z, 256..259 = e ------------
__global__ __launch_bounds__(256) void k_prep(const float* __restrict__ z,
                                              const float* __restrict__ emb,
                                              float* __restrict__ out,
                                              float* __restrict__ ws) {
  __shared__ float lt[64][132];
  __shared__ float sq[128];
  const int tid = threadIdx.x;
  if (blockIdx.x >= 256) {
    // ---- eprep: one code per thread; tiles [ct4][s][kq][n 0..255][8] ----
    const int k = (blockIdx.x - 256) * 256 + tid;   // 0..1023
    if (k == 0) { out[LOSS_OFF] = 0.0f; ((int*)ws)[WS_CNT] = 0; }
    const int ct = k >> 8, n = k & 255;
    const float* er = emb + k * DDIM;
    ushort* e1t = (ushort*)(ws + WS_E1);
    ushort* e2t = (ushort*)(ws + WS_E2);
    float bsum = 0.f;
    for (int s = 0; s < 8; ++s) {
#pragma unroll
      for (int kq = 0; kq < 4; ++kq) {
        const float4 v0 = *(const float4*)(er + s * 32 + kq * 8);
        const float4 v1 = *(const float4*)(er + s * 32 + kq * 8 + 4);
        const float v[8] = {v0.x, v0.y, v0.z, v0.w, v1.x, v1.y, v1.z, v1.w};
        u16x8 h, l;
#pragma unroll
        for (int j = 0; j < 8; ++j) {
          bsum = fmaf(v[j], v[j], bsum);
          h[j] = bf16_rne(v[j]);
          l[j] = bf16_rne(v[j] - bf16f(h[j]));
        }
        const int off = ct * 65536 + s * 8192 + kq * 2048 + n * 8;
        *(u16x8*)(e1t + off) = h;
        *(u16x8*)(e2t + off) = l;
      }
    }
    ws[WS_B + k] = bsum;
    return;
  }
  // ---- zprep: tiles [rt128][s][kq][m 0..127][8] + A_n ----
  const int rt = blockIdx.x;
  const int b = rt >> 3;
  const int hw0 = (rt & 7) << 7;
  ushort* z1t = (ushort*)out;
  ushort* z2t = (ushort*)out + Z2T_OFF;
  const int m = tid & 127, half = tid >> 7;
  const int lc = tid >> 2, lq = tid & 3;
  float as[4] = {0.f, 0.f, 0.f, 0.f};
  for (int p = 0; p < 4; ++p) {
    const float* src = z + b * 262144 + ((p << 6) + lc) * 1024 + hw0 + (lq << 5);
#pragma unroll
    for (int i = 0; i < 8; ++i)
      *(float4*)&lt[lc][(lq << 5) + (i << 2)] = *(const float4*)(src + (i << 2));
    __syncthreads();
    const int s = (p << 1) + half;
#pragma unroll
    for (int kq = 0; kq < 4; ++kq) {
      u16x8 h, l;
#pragma unroll
      for (int j = 0; j < 8; ++j) {
        const float v = lt[(half << 5) + (kq << 3) + j][m];
        as[j & 3] = fmaf(v, v, as[j & 3]);
        h[j] = bf16_rne(v);
        l[j] = bf16_rne(v - bf16f(h[j]));
      }
      const int off = rt * 32768 + ((s << 2) + kq) * 1024 + (m << 3);
      *(u16x8*)(z1t + off) = h;
      *(u16x8*)(z2t + off) = l;
    }
    __syncthreads();
  }
  const float asum = (as[0] + as[1]) + (as[2] + as[3]);
  if (half) sq[m] = asum;
  __syncthreads();
  if (!half) ws[WS_A + rt * 128 + m] = asum + sq[m];
}

// ---------------- B: MFMA score, one block = 128 rows x ALL 1024 codes ------
// 512 thr (8 waves 2x4), 4 ct-strips of 256 cols, 8 K-steps each. LDS 96 KB
// dbuf via global_load_lds, counted vmcnt(6). Online top-2 fold + per-chunk
// (64-code) minima into LDS at strip boundaries; final reduce writes idx,
// gate-list, loss, and the 16 chunk-min arrays for k_refine.
__global__ __launch_bounds__(512, 2) void k_score(float* out,
                                                  float* __restrict__ ws) {
  __shared__ __align__(16) ushort lds[2][24576];  // 2 x 48 KB
  __shared__ float Bs[1024];
  __shared__ float pvs[2048];                     // [chunk 16][row 128]
  __shared__ float sm2[8];
  const int tid = threadIdx.x;
  const int rt = blockIdx.x;           // 0..255
  const int row0 = rt << 7;
  const ushort* z1t = (const ushort*)out;
  const ushort* z2t = (const ushort*)out + Z2T_OFF;
  const ushort* e1t = (const ushort*)(ws + WS_E1);
  const ushort* e2t = (const ushort*)(ws + WS_E2);
  const int w = tid >> 6, L = tid & 63;
  const int l15 = L & 15, kq = L >> 4;
  const int wr = w >> 2, wc = w & 3;

  // prologue loads: Bs (LDS), Av (regs)
  Bs[tid] = ws[WS_B + tid];
  Bs[tid + 512] = ws[WS_B + tid + 512];
  float Av[4][4];
#pragma unroll
  for (int mi = 0; mi < 4; ++mi)
#pragma unroll
    for (int r = 0; r < 4; ++r)
      Av[mi][r] = ws[WS_A + row0 + (wr << 6) + (mi << 4) + (kq << 2) + r];
  asm volatile("s_waitcnt vmcnt(0)" ::: "memory");
  __builtin_amdgcn_sched_barrier(0);
  __syncthreads();

  // staging bases: 48 x 1KB slabs per step; wave w owns flat slabs w*6..w*6+5
  const ushort* cbase[6];
  bool cisz[6];
#pragma unroll
  for (int c = 0; c < 6; ++c) {
    const int f = w * 6 + c;
    if (f < 8)       { cbase[c] = z1t + rt * 32768 + (f << 9) + (L << 3); cisz[c] = true; }
    else if (f < 16) { cbase[c] = z2t + rt * 32768 + ((f - 8) << 9) + (L << 3); cisz[c] = true; }
    else if (f < 32) { cbase[c] = e1t + ((f - 16) << 9) + (L << 3); cisz[c] = false; }
    else             { cbase[c] = e2t + ((f - 32) << 9) + (L << 3); cisz[c] = false; }
  }
  auto stage = [&](int q, int bf) {
    const int s = q & 7, ct = q >> 3;
    const int zoff = s << 12;
    const int eoff = (ct << 16) + (s << 13);
#pragma unroll
    for (int c = 0; c < 6; ++c) {
      const ushort* src = cbase[c] + (cisz[c] ? zoff : eoff);
      gld16(&lds[bf][(w * 6 + c) << 9], src);
    }
  };

  f32x4 acc[4][4];
  float v1[4][4], v2[4][4];
  int i1[4][4];
#pragma unroll
  for (int mi = 0; mi < 4; ++mi)
#pragma unroll
    for (int r = 0; r < 4; ++r) {
      acc[mi][r] = (f32x4){0.f, 0.f, 0.f, 0.f};
      v1[mi][r] = 3.0e38f; v2[mi][r] = 3.0e38f; i1[mi][r] = 0;
    }

  stage(0, 0);
  stage(1, 1);

  auto body = [&](int q, int cur, bool last) {
    if (!last) asm volatile("s_waitcnt vmcnt(6)" ::: "memory");
    else       asm volatile("s_waitcnt vmcnt(0)" ::: "memory");
    __builtin_amdgcn_sched_barrier(0);
    __builtin_amdgcn_s_barrier();
    __builtin_amdgcn_sched_barrier(0);
    const ushort* lb = lds[cur];
    bf16x8 a1[4], a2[4], b1[4], b2[4];
#pragma unroll
    for (int mi = 0; mi < 4; ++mi) {
      const int off = (kq << 10) + (((wr << 6) + (mi << 4) + l15) << 3);
      a1[mi] = *(const bf16x8*)&lb[off];
      a2[mi] = *(const bf16x8*)&lb[4096 + off];
    }
#pragma unroll
    for (int nj = 0; nj < 4; ++nj) {
      const int off = (kq << 11) + (((wc << 6) + (nj << 4) + l15) << 3);
      b1[nj] = *(const bf16x8*)&lb[8192 + off];
      b2[nj] = *(const bf16x8*)&lb[16384 + off];
    }
    asm volatile("s_waitcnt lgkmcnt(0)" ::: "memory");
    __builtin_amdgcn_sched_barrier(0);
    __builtin_amdgcn_s_barrier();
    __builtin_amdgcn_sched_barrier(0);
    if (q < 30) stage(q + 2, cur);
    __builtin_amdgcn_s_setprio(1);
#pragma unroll
    for (int mi = 0; mi < 4; ++mi)
#pragma unroll
      for (int nj = 0; nj < 4; ++nj) {
        acc[mi][nj] = __builtin_amdgcn_mfma_f32_16x16x32_bf16(a2[mi], b1[nj], acc[mi][nj], 0, 0, 0);
        acc[mi][nj] = __builtin_amdgcn_mfma_f32_16x16x32_bf16(a1[mi], b2[nj], acc[mi][nj], 0, 0, 0);
        acc[mi][nj] = __builtin_amdgcn_mfma_f32_16x16x32_bf16(a1[mi], b1[nj], acc[mi][nj], 0, 0, 0);
      }
    __builtin_amdgcn_s_setprio(0);
    if ((q & 7) == 7) {   // ct-strip boundary: fold scores + chunk minima
      const int ct = q >> 3;
      float bb[4];
#pragma unroll
      for (int nj = 0; nj < 4; ++nj)
        bb[nj] = Bs[(ct << 8) + (wc << 6) + (nj << 4) + l15];
      float cm[4][4];
#pragma unroll
      for (int mi = 0; mi < 4; ++mi)
#pragma unroll
        for (int r = 0; r < 4; ++r) cm[mi][r] = 3.0e38f;
#pragma unroll
      for (int mi = 0; mi < 4; ++mi)
#pragma unroll
        for (int nj = 0; nj < 4; ++nj) {
          const int kg = (ct << 8) + (wc << 6) + (nj << 4) + l15;
#pragma unroll
          for (int r = 0; r < 4; ++r) {
            const float sc = fmaf(-2.0f, acc[mi][nj][r], Av[mi][r] + bb[nj]);
            if (sc < v1[mi][r]) { v2[mi][r] = v1[mi][r]; v1[mi][r] = sc; i1[mi][r] = kg; }
            else if (sc < v2[mi][r]) v2[mi][r] = sc;
            cm[mi][r] = fminf(cm[mi][r], sc);
          }
          acc[mi][nj] = (f32x4){0.f, 0.f, 0.f, 0.f};
        }
      // per-chunk min across the 16 l15 lanes -> pvs[(ct*4+wc)][rowl]
#pragma unroll
      for (int mi = 0; mi < 4; ++mi)
#pragma unroll
        for (int r = 0; r < 4; ++r) {
          float cv = cm[mi][r];
#pragma unroll
          for (int o = 1; o < 16; o <<= 1) cv = fminf(cv, __shfl_xor(cv, o));
          if (l15 == 0) {
            const int rowl = (wr << 6) + (mi << 4) + (kq << 2) + r;
            pvs[((ct << 2) | wc) * 128 + rowl] = cv;
          }
        }
    }
  };

  for (int q = 0; q < 31; ++q) body(q, q & 1, false);
  body(31, 1, true);

  // cross-l15 reduce of global top-2 (once per block)
#pragma unroll
  for (int mi = 0; mi < 4; ++mi)
#pragma unroll
    for (int r = 0; r < 4; ++r) {
      float a = v1[mi][r], bb = v2[mi][r];
      int ii = i1[mi][r];
#pragma unroll
      for (int o = 1; o < 16; o <<= 1) {
        const float oa = __shfl_xor(a, o);
        const float ob = __shfl_xor(bb, o);
        const int oi = __shfl_xor(ii, o);
        bb = fminf(fminf(bb, ob), fmaxf(a, oa));
        if (oa < a || (oa == a && oi < ii)) { a = oa; ii = oi; }
      }
      v1[mi][r] = a; v2[mi][r] = bb; i1[mi][r] = ii;
    }

  // cross-wave merge via LDS (staging done; reuse lds[0])
  __syncthreads();
  // flush chunk minima to ws (pvs complete after the barrier)
  for (int i = tid; i < 2048; i += 512) {
    const int c = i >> 7, rl = i & 127;
    ws[WS_PV + (c << 15) + row0 + rl] = pvs[i];
  }
  float* red = (float*)&lds[0][0];   // [4 wc][128 rows][3]
  if (l15 == 0) {
#pragma unroll
    for (int mi = 0; mi < 4; ++mi)
#pragma unroll
      for (int r = 0; r < 4; ++r) {
        const int rl = (wr << 6) + (mi << 4) + (kq << 2) + r;
        const int b3 = (wc * 128 + rl) * 3;
        red[b3] = v1[mi][r];
        red[b3 + 1] = v2[mi][r];
        red[b3 + 2] = (float)i1[mi][r];
      }
  }
  __syncthreads();
  float losss = 0.f;
  if (tid < 128) {
    float fv1 = 3.0e38f, fv2 = 3.0e38f;
    int fi = 0;
#pragma unroll
    for (int c = 0; c < 4; ++c) {
      const int b3 = (c * 128 + tid) * 3;
      const float a1 = red[b3], a2 = red[b3 + 1];
      const int ai = (int)red[b3 + 2];
      if (a1 < fv1 || (a1 == fv1 && ai < fi)) { fv2 = fminf(fv1, a2); fv1 = a1; fi = ai; }
      else fv2 = fminf(fv2, a1);
    }
    const int row = row0 + tid;
    out[IDX_OFF + row] = (float)fi;
    if (fv2 - fv1 < REFINE_THR) {
      const int slot = atomicAdd((int*)ws + WS_CNT, 1);
      ((int*)ws)[WS_LIST + slot] = row;
    }
    losss = fv1;
  }
#pragma unroll
  for (int o = 32; o; o >>= 1) losss += __shfl_down(losss, o);
  if ((tid & 63) == 0) sm2[tid >> 6] = losss;
  __syncthreads();
  if (tid == 0) {
    float t = 0.f;
#pragma unroll
    for (int i = 0; i < 8; ++i) t += sm2[i];
    atomicAdd(out + LOSS_OFF, t * (1.25f / 8388608.0f));
  }
}

// ---------------- B3: exact re-solve, candidate chunks only (R8-proven) -----
__global__ __launch_bounds__(256) void k_refine(const float* __restrict__ z,
                                                const float* __restrict__ emb,
                                                const float* __restrict__ ws,
                                                float* __restrict__ out) {
  __shared__ float zs[4][256];
  const int tid = threadIdx.x;
  const int w = tid >> 6, L = tid & 63;
  const int wg = blockIdx.x * 4 + w;
  const int cnt = ((const int*)ws)[WS_CNT];
  for (int e = wg; e < cnt; e += 1024) {
    const int row = ((const int*)ws)[WS_LIST + e];
    const int b = row >> 10, hw = row & 1023;
#pragma unroll
    for (int q = 0; q < 4; ++q)
      zs[w][(q << 6) + L] = z[b * 262144 + (((q << 6) + L) << 10) + hw];
    asm volatile("s_waitcnt lgkmcnt(0)" ::: "memory");
    float v1c = (L < 16) ? ws[WS_PV + (L << 15) + row] : 3.0e38f;
    float v1 = v1c;
#pragma unroll
    for (int o = 1; o < 64; o <<= 1) v1 = fminf(v1, __shfl_xor(v1, o));
    const float A = ws[WS_A + row];
    float bv = 3.0e38f;
    int bk = 0;
    for (int tc = 0; tc < 16; ++tc) {
      const float bc = __shfl(v1c, tc);
      if (bc <= v1 + REFINE_THR) {
        const int k = (tc << 6) + L;         // chunk tc = codes 64*tc..64*tc+63
        const float* er = emb + k * DDIM;
        float s = 0.f;
        for (int d = 0; d < DDIM; ++d) s = fmaf(zs[w][d], er[d], s);  // round-3 chain
        const float sc = fmaf(-2.0f, s, A + ws[WS_B + k]);
        if (sc < bv) { bv = sc; bk = k; }    // tc ascending => lowest k kept
      }
    }
#pragma unroll
    for (int o = 1; o < 64; o <<= 1) {
      const float ov = __shfl_xor(bv, o);
      const int ok = __shfl_xor(bk, o);
      if (ov < bv || (ov == bv && ok < bk)) { bv = ov; bk = ok; }
    }
    if (L == 0) out[IDX_OFF + row] = (float)bk;
  }
}

// ---------------- C: z_q gather (pure) ----------------
__global__ __launch_bounds__(256) void k_gather(const float* __restrict__ emb,
                                                float* __restrict__ out) {
  const int tid = threadIdx.x;
  const int e0 = (blockIdx.x * 256 + tid) * 16;
  const int b = e0 >> 18;
  const int c = (e0 >> 10) & 255;
  const int n0 = (b << 10) + (e0 & 1023);
#pragma unroll
  for (int g = 0; g < 4; ++g) {
    float q[4];
#pragma unroll
    for (int j = 0; j < 4; ++j) {
      const int id = (int)(out[IDX_OFF + n0 + g * 4 + j] + 0.5f);
      q[j] = emb[id * DDIM + c];
    }
    const float4 qv = {q[0], q[1], q[2], q[3]};
    *(float4*)(out + e0 + g * 4) = qv;
  }
}

extern "C" void kernel_launch(void* const* d_in, const int* in_sizes, int n_in,
                              void* d_out, int out_size, void* d_ws, size_t ws_size,
                              hipStream_t stream) {
  const float* z = (const float*)d_in[0];
  const float* emb = (const float*)d_in[1];
  float* out = (float*)d_out;
  float* ws = (float*)d_ws;

  k_prep<<<260, 256, 0, stream>>>(z, emb, out, ws);
  k_score<<<256, 512, 0, stream>>>(out, ws);
  k_refine<<<256, 256, 0, stream>>>(z, emb, ws, out);
  k_gather<<<2048, 256, 0, stream>>>(emb, out);
}